// Round 9
// baseline (140.022 us; speedup 1.0000x reference)
//
#include <hip/hip_runtime.h>

#define SP    65536      // 16*64*64 spatial voxels
#define DD    16
#define HH    64
#define WW    64
#define CIN   64
#define COUT  64

#define LOG2E 1.44269504f

// ws layout (fp32): q [64][SP] | k [64][SP] | v [64][SP]   (48 MB)
// LESSON LEDGER:
// r10: bf16 STORAGE of k fails accuracy. Intermediates fp32 in HBM.
// r11: proj = bf16x3 split MFMA (wh*xh+wh*xl+wl*xh); q pre-scaled by LOG2E.
// r12: no-LDS attn w/ FULLY-UNROLLED walk -> hoisted loads -> 374MB spill.
// r13: I-cache theory FALSIFIED.
// r14+r17: ANY min-waves launch_bounds on attn spills. attn runs uncapped.
// r16+r17: in-register w split = proj regression (~2x); w-via-LDS kept.
// r18: attn v10 direct-global (no LDS/barrier) passed, total 115.7 (best).
// r19 (THIS = DIAGNOSTIC ROUND): the additive time ledger is inconsistent
// (attn inferred ~50 but absent from top-5 whose floor is 43.3us fills).
// attn is launched TWICE (2nd is idempotent: same inputs, same output
// values) to force it into the counter window with full PMCs. proj is then
// pinned by subtraction. Total deliberately ~= best + attn_dur. Next round
// reverts to single launch and targets whichever kernel the counters
// convict. Kernels themselves are UNCHANGED from r18.

typedef __attribute__((ext_vector_type(8))) short bf16x8;   // 8 bf16 = 4 VGPRs
typedef __attribute__((ext_vector_type(4))) float f32x4;    // MFMA acc

__device__ __forceinline__ unsigned short f2bf(float f) {   // RNE f32->bf16
    const unsigned u = __float_as_uint(f);
    return (unsigned short)((u + 0x7FFFu + ((u >> 16) & 1u)) >> 16);
}
__device__ __forceinline__ float bf2f(unsigned short h) {
    return __uint_as_float((unsigned)h << 16);
}

// proj v2 (r11 form): per block 64 positions x all 64 outs, one matrix
// (grid.y); 3072 blocks. K=64 in LDS once. x staged TRANSPOSED [j][c]
// hi/lo; w staged [o][c] hi/lo VIA LDS. A/B both pack 8 consecutive cin ->
// same k-permutation on both operands -> contraction layout-safe.
// C/D layout (HW-verified): col=lane&15, row=(lane>>4)*4+reg.
__global__ __launch_bounds__(256) void proj(const float* __restrict__ x,
                                            const float* __restrict__ wq,
                                            const float* __restrict__ wk,
                                            const float* __restrict__ wv,
                                            float* __restrict__ q,
                                            float* __restrict__ k,
                                            float* __restrict__ v) {
    __shared__ __align__(16) unsigned short xh [64][72];   // [j][c] hi, 9 KB
    __shared__ __align__(16) unsigned short xlo[64][72];   // [j][c] lo
    __shared__ __align__(16) unsigned short wh [64][72];   // [o][c] hi
    __shared__ __align__(16) unsigned short wlo[64][72];   // 36.9 KB -> 4 blk/CU

    const int t  = threadIdx.x;
    const int p0 = blockIdx.x * 64;
    const int m  = blockIdx.y;

    const float* __restrict__ wsel = (m == 0) ? wq : (m == 1) ? wk : wv;
    float* __restrict__       osel = (m == 0) ? q  : (m == 1) ? k  : v;

#pragma unroll
    for (int i = 0; i < 2; ++i) {
        const int f  = t + 256 * i;          // 0..511
        const int c2 = (f >> 4) * 2;
        const int jj = f & 15;
        const float4 a = *(const float4*)(x + c2 * SP + p0 + jj * 4);
        const float4 b = *(const float4*)(x + (c2 + 1) * SP + p0 + jj * 4);
        const float* af = (const float*)&a;
        const float* bf = (const float*)&b;
#pragma unroll
        for (int e = 0; e < 4; ++e) {
            const int j = jj * 4 + e;
            const unsigned short ah = f2bf(af[e]);
            const unsigned short bh = f2bf(bf[e]);
            const unsigned short al = f2bf(af[e] - bf2f(ah));
            const unsigned short bl = f2bf(bf[e] - bf2f(bh));
            *(unsigned*)&xh [j][c2] = (unsigned)ah | ((unsigned)bh << 16);
            *(unsigned*)&xlo[j][c2] = (unsigned)al | ((unsigned)bl << 16);
        }
    }
#pragma unroll
    for (int i = 0; i < 4; ++i) {
        const int f  = t + 256 * i;          // 0..1023
        const int o  = f >> 4;
        const int jj = f & 15;
        const float4 w4 = *(const float4*)(wsel + o * CIN + jj * 4);
        const float* wf = (const float*)&w4;
        unsigned short h0 = f2bf(wf[0]), h1 = f2bf(wf[1]);
        unsigned short h2 = f2bf(wf[2]), h3 = f2bf(wf[3]);
        unsigned short l0 = f2bf(wf[0] - bf2f(h0)), l1 = f2bf(wf[1] - bf2f(h1));
        unsigned short l2 = f2bf(wf[2] - bf2f(h2)), l3 = f2bf(wf[3] - bf2f(h3));
        *(uint2*)&wh [o][jj * 4] = make_uint2((unsigned)h0 | ((unsigned)h1 << 16),
                                              (unsigned)h2 | ((unsigned)h3 << 16));
        *(uint2*)&wlo[o][jj * 4] = make_uint2((unsigned)l0 | ((unsigned)l1 << 16),
                                              (unsigned)l2 | ((unsigned)l3 << 16));
    }
    __syncthreads();

    const int lane  = t & 63;
    const int wid   = t >> 6;                // wave -> 16-out slice
    const int lo16  = lane & 15;
    const int lg    = lane >> 4;             // 0..3 k-group
    const int otile = wid * 16;

    const bf16x8 Ah0 = *(const bf16x8*)&wh [otile + lo16][lg * 8];
    const bf16x8 Ah1 = *(const bf16x8*)&wh [otile + lo16][32 + lg * 8];
    const bf16x8 Al0 = *(const bf16x8*)&wlo[otile + lo16][lg * 8];
    const bf16x8 Al1 = *(const bf16x8*)&wlo[otile + lo16][32 + lg * 8];

    const float scale = (m == 0) ? LOG2E : 1.f;   // fold exp2 prescale into q

#pragma unroll
    for (int jt = 0; jt < 4; ++jt) {
        const int jr = jt * 16 + lo16;
        const bf16x8 Bh0 = *(const bf16x8*)&xh [jr][lg * 8];
        const bf16x8 Bl0 = *(const bf16x8*)&xlo[jr][lg * 8];
        const bf16x8 Bh1 = *(const bf16x8*)&xh [jr][32 + lg * 8];
        const bf16x8 Bl1 = *(const bf16x8*)&xlo[jr][32 + lg * 8];
        f32x4 hh = {0.f, 0.f, 0.f, 0.f};     // 3 independent chains for ILP
        f32x4 hl = {0.f, 0.f, 0.f, 0.f};
        f32x4 lh = {0.f, 0.f, 0.f, 0.f};
        hh = __builtin_amdgcn_mfma_f32_16x16x32_bf16(Ah0, Bh0, hh, 0, 0, 0);
        hl = __builtin_amdgcn_mfma_f32_16x16x32_bf16(Ah0, Bl0, hl, 0, 0, 0);
        lh = __builtin_amdgcn_mfma_f32_16x16x32_bf16(Al0, Bh0, lh, 0, 0, 0);
        hh = __builtin_amdgcn_mfma_f32_16x16x32_bf16(Ah1, Bh1, hh, 0, 0, 0);
        hl = __builtin_amdgcn_mfma_f32_16x16x32_bf16(Ah1, Bl1, hl, 0, 0, 0);
        lh = __builtin_amdgcn_mfma_f32_16x16x32_bf16(Al1, Bh1, lh, 0, 0, 0);
        float* op = osel + (otile + lg * 4) * SP + p0 + jt * 16 + lo16;
#pragma unroll
        for (int r = 0; r < 4; ++r)
            op[r * SP] = (hh[r] + hl[r] + lh[r]) * scale;   // 4 rows x 64B, coalesced
    }
}

// DPP shifts within 16-lane rows; bound_ctrl=1 -> out-of-row reads 0 =
// exactly the w-boundary zero-pad.
__device__ __forceinline__ float dpp_shr1(float x) {   // lane i <- lane i-1
    return __int_as_float(__builtin_amdgcn_mov_dpp(__float_as_int(x), 0x111, 0xf, 0xf, true));
}
__device__ __forceinline__ float dpp_shl1(float x) {   // lane i <- lane i+1
    return __int_as_float(__builtin_amdgcn_mov_dpp(__float_as_int(x), 0x101, 0xf, 0xf, true));
}

// attn v10 walk (UNCHANGED from r18): thread = 1 float4 output; 9 (kd,kh)
// rows read DIRECTLY from global. unroll(1) on kd bounds in-flight loads.
// AXIS 0/1: rc row-constant -> folded into krow (bit-identical).
// OOB rows: address clamped to 0, value zeroed (k=0 -> exp(q*rel), v=0).
template<int AXIS>
__device__ __forceinline__ void attn_walk(const float* __restrict__ kc,
                                          const float* __restrict__ vc,
                                          const float (&ql)[4],
                                          float r0, float r1, float r2,
                                          int wg, int dabs, int habs,
                                          float (&s)[4], float (&a)[4]) {
#pragma unroll 1
    for (int kd = 0; kd < 3; ++kd) {
        const float rdd = (kd == 0) ? r0 : (kd == 1) ? r1 : r2;
        const int dpg   = dabs - 1 + kd;
        const bool okd  = (unsigned)dpg < (unsigned)DD;
#pragma unroll
        for (int kh = 0; kh < 3; ++kh) {
            const float rkh = (kh == 0) ? r0 : (kh == 1) ? r1 : r2;
            const float rr  = (AXIS == 0) ? rdd : rkh;
            const int hpg   = habs - 1 + kh;
            const bool ok   = okd && ((unsigned)hpg < (unsigned)HH);
            const int off   = ok ? ((dpg * HH + hpg) * WW + wg * 4) : 0;
            float4 km = *(const float4*)(kc + off);
            float4 vm = *(const float4*)(vc + off);
            if (!ok) {
                km = make_float4(0.f, 0.f, 0.f, 0.f);
                vm = make_float4(0.f, 0.f, 0.f, 0.f);
            }
            const float kl = dpp_shr1(km.w), kr = dpp_shl1(km.x);
            const float vl = dpp_shr1(vm.w), vr = dpp_shl1(vm.x);
            float krow[6] = { kl, km.x, km.y, km.z, km.w, kr };
            const float vrow[6] = { vl, vm.x, vm.y, vm.z, vm.w, vr };
            if (AXIS != 2) {                 // hoist row-constant rel
#pragma unroll
                for (int j = 0; j < 6; ++j) krow[j] += rr;
            }
#pragma unroll
            for (int wi = 0; wi < 4; ++wi) {
                const float qv = ql[wi];
#pragma unroll
                for (int kw = 0; kw < 3; ++kw) {
                    const float arg = (AXIS == 2)
                                    ? (krow[wi + kw] + ((kw == 0) ? r0 : (kw == 1) ? r1 : r2))
                                    : krow[wi + kw];
                    const float e = __builtin_amdgcn_exp2f(qv * arg);
                    s[wi] += e;
                    a[wi] = fmaf(e, vrow[wi + kw], a[wi]);
                }
            }
        }
    }
}

// attn v10 (UNCHANGED): block = (dtile4 x htile4, o); thread = ONE float4.
// NO LDS, NO barrier. No launch_bounds cap (r14/r17).
__global__ __launch_bounds__(256) void attn(const float* __restrict__ kbuf,
                                            const float* __restrict__ vbuf,
                                            const float* __restrict__ qbuf,
                                            const float* __restrict__ rel_d,
                                            const float* __restrict__ rel_h,
                                            const float* __restrict__ rel_w,
                                            float* __restrict__ out) {
    const int dt = blockIdx.x;       // 0..3
    const int ht = blockIdx.y;       // 0..15
    const int o  = blockIdx.z;       // 0..63

    const int d0 = dt * 4;
    const int h0 = ht * 4;
    const int t  = threadIdx.x;

    const float* __restrict__ kc = kbuf + o * SP;
    const float* __restrict__ vc = vbuf + o * SP;

    const int wg = t & 15;           // float4 in w
    const int hl = (t >> 4) & 3;     // local h
    const int dl = t >> 6;           // local d (== wave id)

    const int dabs = d0 + dl;
    const int habs = h0 + hl;

    float ql[4];
    {
        const float4 q4 = *(const float4*)(qbuf + o * SP + (dabs * HH + habs) * WW + wg * 4);
        ql[0] = q4.x; ql[1] = q4.y;            // q pre-scaled by LOG2E in proj
        ql[2] = q4.z; ql[3] = q4.w;
    }

    float s[4] = {};
    float a[4] = {};

    if (o < 21) {
        attn_walk<0>(kc, vc, ql, rel_d[o * 3], rel_d[o * 3 + 1], rel_d[o * 3 + 2],
                     wg, dabs, habs, s, a);
    } else if (o < 42) {
        const int b = o - 21;
        attn_walk<1>(kc, vc, ql, rel_h[b * 3], rel_h[b * 3 + 1], rel_h[b * 3 + 2],
                     wg, dabs, habs, s, a);
    } else {
        const int b = o - 42;
        attn_walk<2>(kc, vc, ql, rel_w[b * 3], rel_w[b * 3 + 1], rel_w[b * 3 + 2],
                     wg, dabs, habs, s, a);
    }

    float4 ov;
    ov.x = a[0] * __builtin_amdgcn_rcpf(s[0]);
    ov.y = a[1] * __builtin_amdgcn_rcpf(s[1]);
    ov.z = a[2] * __builtin_amdgcn_rcpf(s[2]);
    ov.w = a[3] * __builtin_amdgcn_rcpf(s[3]);
    *(float4*)(out + o * SP + (dabs * HH + habs) * WW + wg * 4) = ov;
}

extern "C" void kernel_launch(void* const* d_in, const int* in_sizes, int n_in,
                              void* d_out, int out_size, void* d_ws, size_t ws_size,
                              hipStream_t stream) {
    const float* x     = (const float*)d_in[0];
    const float* w_q   = (const float*)d_in[1];
    const float* w_k   = (const float*)d_in[2];
    const float* w_v   = (const float*)d_in[3];
    const float* rel_d = (const float*)d_in[4];
    const float* rel_h = (const float*)d_in[5];
    const float* rel_w = (const float*)d_in[6];
    float* out = (float*)d_out;

    float* ws = (float*)d_ws;
    float* q  = ws;
    float* k  = ws + (size_t)COUT * SP;
    float* v  = ws + 2 * (size_t)COUT * SP;

    proj<<<dim3(SP / 64, 3), 256, 0, stream>>>(x, w_q, w_k, w_v, q, k, v);
    // DIAGNOSTIC (r19): attn launched twice. 2nd dispatch is idempotent
    // (same inputs -> identical output values) and exists only to force
    // attn into the rocprof top-5 window with full counters. Remove next
    // round once attn's true dur/VALUBusy/occupancy/FETCH are known.
    attn<<<dim3(4, 16, 64), 256, 0, stream>>>(k, v, q, rel_d, rel_h, rel_w, out);
    attn<<<dim3(4, 16, 64), 256, 0, stream>>>(k, v, q, rel_d, rel_h, rel_w, out);
}

// Round 10
// 136.508 us; speedup vs baseline: 1.0257x; 1.0257x over previous
//
#include <hip/hip_runtime.h>

#define SP    65536      // 16*64*64 spatial voxels
#define DD    16
#define HH    64
#define WW    64
#define CIN   64
#define COUT  64

#define LOG2E 1.44269504f

// ws layout: q|k|v fp32 [64][SP] (50.3MB), then xhT|xlT bf16 [SP][64]
// (16.8MB), then wsplit 3x(hi 4096 + lo 4096) ushorts (48KB). ~67MB total.
// LESSON LEDGER:
// r10: bf16 STORAGE of k fails accuracy. k stays fp32 in HBM.
// r11: bf16x3 split MFMA (wh*xh+wh*xl+wl*xh); q pre-scaled by LOG2E.
// r12: unbounded unroll of global loads -> hoist -> scratch spill.
// r14+r17: ANY min-waves launch_bounds on attn spills. attn runs uncapped.
// r19 DIAGNOSTIC (2x attn launch): attn v10 = 24.3us WALL (was hiding under
// the 43us fills). => proj ~= 47us, 4.4x over its ~11us BW floor. rocprof
// dur for LDS-heavy kernels is PMC-inflated ~2x (r1 "53.7" attn was ~28
// wall) - never trust replay durations as wall time again.
// r20 (this): proj split into:
//   A) splitk (once): x -> LDS-transpose -> pre-split bf16 xhT/xlT [SP][64];
//      w -> pre-split wh/wl. Pure streaming, ~34MB.
//   B) proj: NO LDS, NO barrier, NO split-VALU. A/B frags = direct 16B
//      coalesced global loads of pre-split bf16; 24 MFMA; fp32 stores.
// Bit-identical arithmetic to r18 => absmax must stay exactly 0.015625.

typedef __attribute__((ext_vector_type(8))) short bf16x8;   // 8 bf16 = 4 VGPRs
typedef __attribute__((ext_vector_type(4))) float f32x4;    // MFMA acc

__device__ __forceinline__ unsigned short f2bf(float f) {   // RNE f32->bf16
    const unsigned u = __float_as_uint(f);
    return (unsigned short)((u + 0x7FFFu + ((u >> 16) & 1u)) >> 16);
}
__device__ __forceinline__ float bf2f(unsigned short h) {
    return __uint_as_float((unsigned)h << 16);
}

// kernel A: blocks 0..1023 transpose+split one 64-pos x tile each;
// blocks 1024..1026 split one w matrix each (no LDS needed - layout kept).
__global__ __launch_bounds__(256) void splitk(const float* __restrict__ x,
                                              const float* __restrict__ wq,
                                              const float* __restrict__ wk,
                                              const float* __restrict__ wv,
                                              unsigned short* __restrict__ xhT,
                                              unsigned short* __restrict__ xlT,
                                              unsigned short* __restrict__ wsp) {
    const int bid = blockIdx.x;
    const int t   = threadIdx.x;

    if (bid >= 1024) {               // w split: 64x64 fp32 -> hi/lo bf16
        const int m = bid - 1024;
        const float* __restrict__ wsel = (m == 0) ? wq : (m == 1) ? wk : wv;
        unsigned short* dh = wsp + m * 8192;
        unsigned short* dl = dh + 4096;
#pragma unroll
        for (int i = 0; i < 4; ++i) {
            const int f = t + 256 * i;           // float4 idx 0..1023
            const float4 w4 = *(const float4*)(wsel + f * 4);
            const float* wf = (const float*)&w4;
            unsigned short h[4], l[4];
#pragma unroll
            for (int e = 0; e < 4; ++e) {
                h[e] = f2bf(wf[e]);
                l[e] = f2bf(wf[e] - bf2f(h[e]));
            }
            *(uint2*)(dh + f * 4) = make_uint2((unsigned)h[0] | ((unsigned)h[1] << 16),
                                               (unsigned)h[2] | ((unsigned)h[3] << 16));
            *(uint2*)(dl + f * 4) = make_uint2((unsigned)l[0] | ((unsigned)l[1] << 16),
                                               (unsigned)l[2] | ((unsigned)l[3] << 16));
        }
        return;
    }

    // x tile transpose+split via LDS (proj-v2's proven stage pattern)
    __shared__ __align__(16) unsigned short sh[64][72];   // [p][c] pitch 72
    __shared__ __align__(16) unsigned short sl[64][72];

    const int p0 = bid * 64;
#pragma unroll
    for (int i = 0; i < 2; ++i) {
        const int f  = t + 256 * i;          // 0..511
        const int c2 = (f >> 4) * 2;
        const int jj = f & 15;
        const float4 a = *(const float4*)(x + c2 * SP + p0 + jj * 4);
        const float4 b = *(const float4*)(x + (c2 + 1) * SP + p0 + jj * 4);
        const float* af = (const float*)&a;
        const float* bf = (const float*)&b;
#pragma unroll
        for (int e = 0; e < 4; ++e) {
            const int j = jj * 4 + e;
            const unsigned short ah = f2bf(af[e]);
            const unsigned short bh = f2bf(bf[e]);
            const unsigned short al = f2bf(af[e] - bf2f(ah));
            const unsigned short bl = f2bf(bf[e] - bf2f(bh));
            *(unsigned*)&sh[j][c2] = (unsigned)ah | ((unsigned)bh << 16);
            *(unsigned*)&sl[j][c2] = (unsigned)al | ((unsigned)bl << 16);
        }
    }
    __syncthreads();

    // copy out transposed rows: 64 rows x 64 ushorts = 1024 8B-granules/array
#pragma unroll
    for (int i = 0; i < 4; ++i) {
        const int idx = t + 256 * i;         // 0..1023
        const int row = idx >> 4;
        const int seg = idx & 15;            // 4-ushort granule
        const uint2 hv = *(const uint2*)&sh[row][seg * 4];   // 8B aligned (144|8)
        const uint2 lv = *(const uint2*)&sl[row][seg * 4];
        *(uint2*)(xhT + (size_t)(p0 + row) * 64 + seg * 4) = hv;
        *(uint2*)(xlT + (size_t)(p0 + row) * 64 + seg * 4) = lv;
    }
}

// kernel B: proj v6 - LDS-free MFMA. Per block: 64 positions x 64 outs x
// one matrix. A/B frags = direct coalesced 16B loads of pre-split bf16
// (each wave's 64 lanes cover one contiguous 2KB row-block; L2/L3-hit).
// A/B both pack 8 consecutive cin -> same k-permutation both operands ->
// contraction layout-permutation-safe.
// C/D layout (HW-verified): col=lane&15, row=(lane>>4)*4+reg.
__global__ __launch_bounds__(256) void proj(const unsigned short* __restrict__ xhT,
                                            const unsigned short* __restrict__ xlT,
                                            const unsigned short* __restrict__ wsp,
                                            float* __restrict__ q,
                                            float* __restrict__ k,
                                            float* __restrict__ v) {
    const int p0 = blockIdx.x * 64;
    const int m  = blockIdx.y;
    float* __restrict__ osel = (m == 0) ? q : (m == 1) ? k : v;
    const unsigned short* wh = wsp + m * 8192;
    const unsigned short* wl = wh + 4096;

    const int lane  = threadIdx.x & 63;
    const int wid   = threadIdx.x >> 6;      // wave -> 16-out slice
    const int lo16  = lane & 15;
    const int lg    = lane >> 4;             // 0..3 k-group
    const int otile = wid * 16;

    const bf16x8 Ah0 = *(const bf16x8*)(wh + (otile + lo16) * 64 + lg * 8);
    const bf16x8 Ah1 = *(const bf16x8*)(wh + (otile + lo16) * 64 + 32 + lg * 8);
    const bf16x8 Al0 = *(const bf16x8*)(wl + (otile + lo16) * 64 + lg * 8);
    const bf16x8 Al1 = *(const bf16x8*)(wl + (otile + lo16) * 64 + 32 + lg * 8);

    const float scale = (m == 0) ? LOG2E : 1.f;   // fold exp2 prescale into q

#pragma unroll 2
    for (int jt = 0; jt < 4; ++jt) {         // unroll 2: bound in-flight loads (r12)
        const int jr = jt * 16 + lo16;
        const unsigned short* xrh = xhT + (size_t)(p0 + jr) * 64;
        const unsigned short* xrl = xlT + (size_t)(p0 + jr) * 64;
        const bf16x8 Bh0 = *(const bf16x8*)(xrh + lg * 8);
        const bf16x8 Bl0 = *(const bf16x8*)(xrl + lg * 8);
        const bf16x8 Bh1 = *(const bf16x8*)(xrh + 32 + lg * 8);
        const bf16x8 Bl1 = *(const bf16x8*)(xrl + 32 + lg * 8);
        f32x4 hh = {0.f, 0.f, 0.f, 0.f};     // 3 independent chains for ILP
        f32x4 hl = {0.f, 0.f, 0.f, 0.f};
        f32x4 lh = {0.f, 0.f, 0.f, 0.f};
        hh = __builtin_amdgcn_mfma_f32_16x16x32_bf16(Ah0, Bh0, hh, 0, 0, 0);
        hl = __builtin_amdgcn_mfma_f32_16x16x32_bf16(Ah0, Bl0, hl, 0, 0, 0);
        lh = __builtin_amdgcn_mfma_f32_16x16x32_bf16(Al0, Bh0, lh, 0, 0, 0);
        hh = __builtin_amdgcn_mfma_f32_16x16x32_bf16(Ah1, Bh1, hh, 0, 0, 0);
        hl = __builtin_amdgcn_mfma_f32_16x16x32_bf16(Ah1, Bl1, hl, 0, 0, 0);
        lh = __builtin_amdgcn_mfma_f32_16x16x32_bf16(Al1, Bh1, lh, 0, 0, 0);
        float* op = osel + (otile + lg * 4) * SP + p0 + jt * 16 + lo16;
#pragma unroll
        for (int r = 0; r < 4; ++r)
            op[r * SP] = (hh[r] + hl[r] + lh[r]) * scale;   // 4 rows x 64B, coalesced
    }
}

// DPP shifts within 16-lane rows; bound_ctrl=1 -> out-of-row reads 0 =
// exactly the w-boundary zero-pad.
__device__ __forceinline__ float dpp_shr1(float x) {   // lane i <- lane i-1
    return __int_as_float(__builtin_amdgcn_mov_dpp(__float_as_int(x), 0x111, 0xf, 0xf, true));
}
__device__ __forceinline__ float dpp_shl1(float x) {   // lane i <- lane i+1
    return __int_as_float(__builtin_amdgcn_mov_dpp(__float_as_int(x), 0x101, 0xf, 0xf, true));
}

// attn v10 (UNCHANGED, 24.3us measured r19): thread = 1 float4 output;
// 9 (kd,kh) rows read DIRECTLY from global. unroll(1) on kd bounds loads.
// OOB rows: address clamped to 0, value zeroed (k=0 -> exp(q*rel), v=0).
template<int AXIS>
__device__ __forceinline__ void attn_walk(const float* __restrict__ kc,
                                          const float* __restrict__ vc,
                                          const float (&ql)[4],
                                          float r0, float r1, float r2,
                                          int wg, int dabs, int habs,
                                          float (&s)[4], float (&a)[4]) {
#pragma unroll 1
    for (int kd = 0; kd < 3; ++kd) {
        const float rdd = (kd == 0) ? r0 : (kd == 1) ? r1 : r2;
        const int dpg   = dabs - 1 + kd;
        const bool okd  = (unsigned)dpg < (unsigned)DD;
#pragma unroll
        for (int kh = 0; kh < 3; ++kh) {
            const float rkh = (kh == 0) ? r0 : (kh == 1) ? r1 : r2;
            const float rr  = (AXIS == 0) ? rdd : rkh;
            const int hpg   = habs - 1 + kh;
            const bool ok   = okd && ((unsigned)hpg < (unsigned)HH);
            const int off   = ok ? ((dpg * HH + hpg) * WW + wg * 4) : 0;
            float4 km = *(const float4*)(kc + off);
            float4 vm = *(const float4*)(vc + off);
            if (!ok) {
                km = make_float4(0.f, 0.f, 0.f, 0.f);
                vm = make_float4(0.f, 0.f, 0.f, 0.f);
            }
            const float kl = dpp_shr1(km.w), kr = dpp_shl1(km.x);
            const float vl = dpp_shr1(vm.w), vr = dpp_shl1(vm.x);
            float krow[6] = { kl, km.x, km.y, km.z, km.w, kr };
            const float vrow[6] = { vl, vm.x, vm.y, vm.z, vm.w, vr };
            if (AXIS != 2) {                 // hoist row-constant rel
#pragma unroll
                for (int j = 0; j < 6; ++j) krow[j] += rr;
            }
#pragma unroll
            for (int wi = 0; wi < 4; ++wi) {
                const float qv = ql[wi];
#pragma unroll
                for (int kw = 0; kw < 3; ++kw) {
                    const float arg = (AXIS == 2)
                                    ? (krow[wi + kw] + ((kw == 0) ? r0 : (kw == 1) ? r1 : r2))
                                    : krow[wi + kw];
                    const float e = __builtin_amdgcn_exp2f(qv * arg);
                    s[wi] += e;
                    a[wi] = fmaf(e, vrow[wi + kw], a[wi]);
                }
            }
        }
    }
}

__global__ __launch_bounds__(256) void attn(const float* __restrict__ kbuf,
                                            const float* __restrict__ vbuf,
                                            const float* __restrict__ qbuf,
                                            const float* __restrict__ rel_d,
                                            const float* __restrict__ rel_h,
                                            const float* __restrict__ rel_w,
                                            float* __restrict__ out) {
    const int dt = blockIdx.x;       // 0..3
    const int ht = blockIdx.y;       // 0..15
    const int o  = blockIdx.z;       // 0..63

    const int d0 = dt * 4;
    const int h0 = ht * 4;
    const int t  = threadIdx.x;

    const float* __restrict__ kc = kbuf + o * SP;
    const float* __restrict__ vc = vbuf + o * SP;

    const int wg = t & 15;           // float4 in w
    const int hl = (t >> 4) & 3;     // local h
    const int dl = t >> 6;           // local d (== wave id)

    const int dabs = d0 + dl;
    const int habs = h0 + hl;

    float ql[4];
    {
        const float4 q4 = *(const float4*)(qbuf + o * SP + (dabs * HH + habs) * WW + wg * 4);
        ql[0] = q4.x; ql[1] = q4.y;            // q pre-scaled by LOG2E in proj
        ql[2] = q4.z; ql[3] = q4.w;
    }

    float s[4] = {};
    float a[4] = {};

    if (o < 21) {
        attn_walk<0>(kc, vc, ql, rel_d[o * 3], rel_d[o * 3 + 1], rel_d[o * 3 + 2],
                     wg, dabs, habs, s, a);
    } else if (o < 42) {
        const int b = o - 21;
        attn_walk<1>(kc, vc, ql, rel_h[b * 3], rel_h[b * 3 + 1], rel_h[b * 3 + 2],
                     wg, dabs, habs, s, a);
    } else {
        const int b = o - 42;
        attn_walk<2>(kc, vc, ql, rel_w[b * 3], rel_w[b * 3 + 1], rel_w[b * 3 + 2],
                     wg, dabs, habs, s, a);
    }

    float4 ov;
    ov.x = a[0] * __builtin_amdgcn_rcpf(s[0]);
    ov.y = a[1] * __builtin_amdgcn_rcpf(s[1]);
    ov.z = a[2] * __builtin_amdgcn_rcpf(s[2]);
    ov.w = a[3] * __builtin_amdgcn_rcpf(s[3]);
    *(float4*)(out + o * SP + (dabs * HH + habs) * WW + wg * 4) = ov;
}

extern "C" void kernel_launch(void* const* d_in, const int* in_sizes, int n_in,
                              void* d_out, int out_size, void* d_ws, size_t ws_size,
                              hipStream_t stream) {
    const float* x     = (const float*)d_in[0];
    const float* w_q   = (const float*)d_in[1];
    const float* w_k   = (const float*)d_in[2];
    const float* w_v   = (const float*)d_in[3];
    const float* rel_d = (const float*)d_in[4];
    const float* rel_h = (const float*)d_in[5];
    const float* rel_w = (const float*)d_in[6];
    float* out = (float*)d_out;

    float* ws = (float*)d_ws;
    float* q  = ws;                              // [64][SP] fp32
    float* k  = ws + (size_t)COUT * SP;
    float* v  = ws + 2 * (size_t)COUT * SP;
    unsigned short* xhT = (unsigned short*)(ws + 3 * (size_t)COUT * SP);
    unsigned short* xlT = xhT + (size_t)CIN * SP;
    unsigned short* wsp = xlT + (size_t)CIN * SP;  // 3 * (4096 hi + 4096 lo)

    splitk<<<dim3(1027), 256, 0, stream>>>(x, w_q, w_k, w_v, xhT, xlT, wsp);
    proj<<<dim3(SP / 64, 3), 256, 0, stream>>>(xhT, xlT, wsp, q, k, v);
    attn<<<dim3(4, 16, 64), 256, 0, stream>>>(k, v, q, rel_d, rel_h, rel_w, out);
}

// Round 11
// 117.618 us; speedup vs baseline: 1.1905x; 1.1606x over previous
//
#include <hip/hip_runtime.h>

#define SP    65536      // 16*64*64 spatial voxels
#define DD    16
#define HH    64
#define WW    64
#define CIN   64
#define COUT  64

#define LOG2E 1.44269504f

// ws layout: q|k|v fp32 [64][SP] (50.3MB) + wsplit 3x(4096 hi + 4096 lo)
// ushorts (48KB).
// LESSON LEDGER:
// r10: bf16 STORAGE of k fails accuracy. k stays fp32 in HBM.
// r11: bf16x3 split MFMA (wh*xh+wh*xl+wl*xh); q pre-scaled by LOG2E.
// r12: unbounded unroll of global loads -> hoist -> scratch spill.
// r14+r17: ANY min-waves launch_bounds on attn spills. attn runs uncapped.
// r16+r17: per-block in-register w SPLIT (the VALU) = ~20us regression in
//      every variant. r13's "merged proj = TLP loss" was MISATTRIBUTED to
//      the grid; the merged kernel contained that same split x3.
// r19 DIAGNOSTIC: attn v10 = 24.3us wall; proj(3-launch) ~= 47us vs 11us
//      floor. rocprof replay dur is PMC-inflated ~2x for LDS kernels.
// r20: xhT pre-transpose + LDS-free proj REGRESSED (68us combined): 3x
//      re-read of xhT via L2-latency gathers + extra 50MB round trip.
// r21 (this): merged proj, split hoisted out:
//   splitw (3 blocks): w -> pre-split wh/wl bf16 (48KB, L2-resident).
//   proj (1024 blocks): x staged ONCE via proven LDS transpose; A-frags =
//   direct 16B loads of pre-split w (zero VALU); 72 MFMA; write q,k,v.
// Bit-identical arithmetic to r8 => absmax must stay exactly 0.015625.

typedef __attribute__((ext_vector_type(8))) short bf16x8;   // 8 bf16 = 4 VGPRs
typedef __attribute__((ext_vector_type(4))) float f32x4;    // MFMA acc

__device__ __forceinline__ unsigned short f2bf(float f) {   // RNE f32->bf16
    const unsigned u = __float_as_uint(f);
    return (unsigned short)((u + 0x7FFFu + ((u >> 16) & 1u)) >> 16);
}
__device__ __forceinline__ float bf2f(unsigned short h) {
    return __uint_as_float((unsigned)h << 16);
}

// splitw: 3 blocks, one 64x64 matrix each -> hi/lo bf16 (layout kept [o][c]).
__global__ __launch_bounds__(256) void splitw(const float* __restrict__ wq,
                                              const float* __restrict__ wk,
                                              const float* __restrict__ wv,
                                              unsigned short* __restrict__ wsp) {
    const int m = blockIdx.x;
    const int t = threadIdx.x;
    const float* __restrict__ wsel = (m == 0) ? wq : (m == 1) ? wk : wv;
    unsigned short* dh = wsp + m * 8192;
    unsigned short* dl = dh + 4096;
#pragma unroll
    for (int i = 0; i < 4; ++i) {
        const int f = t + 256 * i;           // float4 idx 0..1023
        const float4 w4 = *(const float4*)(wsel + f * 4);
        const float* wf = (const float*)&w4;
        unsigned short h[4], l[4];
#pragma unroll
        for (int e = 0; e < 4; ++e) {
            h[e] = f2bf(wf[e]);
            l[e] = f2bf(wf[e] - bf2f(h[e]));
        }
        *(uint2*)(dh + f * 4) = make_uint2((unsigned)h[0] | ((unsigned)h[1] << 16),
                                           (unsigned)h[2] | ((unsigned)h[3] << 16));
        *(uint2*)(dl + f * 4) = make_uint2((unsigned)l[0] | ((unsigned)l[1] << 16),
                                           (unsigned)l[2] | ((unsigned)l[3] << 16));
    }
}

// proj v7 (merged): per block 64 positions x all 64 outs x ALL 3 matrices;
// 1024 blocks. x staged TRANSPOSED [j][c] hi/lo in LDS ONCE (pitch 72:
// b128 frag reads 2-way = free). A-frags = direct 16B coalesced loads of
// pre-split w (4 lanes/64B sector; 48KB L2-resident; ZERO split VALU).
// A/B both pack 8 consecutive cin -> same k-permutation both operands ->
// contraction layout-permutation-safe.
// C/D layout (HW-verified): col=lane&15, row=(lane>>4)*4+reg.
__global__ __launch_bounds__(256) void proj(const float* __restrict__ x,
                                            const unsigned short* __restrict__ wsp,
                                            float* __restrict__ q,
                                            float* __restrict__ k,
                                            float* __restrict__ v) {
    __shared__ __align__(16) unsigned short xh [64][72];   // [j][c] hi, 9.2 KB
    __shared__ __align__(16) unsigned short xlo[64][72];   // [j][c] lo -> 18.4 KB

    const int t  = threadIdx.x;
    const int p0 = blockIdx.x * 64;

    // stage x[c][p0+j] -> xh/xlo[j][c], split hi/lo (residual exact).
#pragma unroll
    for (int i = 0; i < 2; ++i) {
        const int f  = t + 256 * i;          // 0..511
        const int c2 = (f >> 4) * 2;
        const int jj = f & 15;
        const float4 a = *(const float4*)(x + c2 * SP + p0 + jj * 4);
        const float4 b = *(const float4*)(x + (c2 + 1) * SP + p0 + jj * 4);
        const float* af = (const float*)&a;
        const float* bf = (const float*)&b;
#pragma unroll
        for (int e = 0; e < 4; ++e) {
            const int j = jj * 4 + e;
            const unsigned short ah = f2bf(af[e]);
            const unsigned short bh = f2bf(bf[e]);
            const unsigned short al = f2bf(af[e] - bf2f(ah));
            const unsigned short bl = f2bf(bf[e] - bf2f(bh));
            *(unsigned*)&xh [j][c2] = (unsigned)ah | ((unsigned)bh << 16);
            *(unsigned*)&xlo[j][c2] = (unsigned)al | ((unsigned)bl << 16);
        }
    }

    const int lane  = t & 63;
    const int wid   = t >> 6;                // wave -> 16-out slice
    const int lo16  = lane & 15;
    const int lg    = lane >> 4;             // 0..3 k-group
    const int otile = wid * 16;

    // A-frags for all 3 matrices: 12 x 16B loads, zero VALU (pre-split)
    bf16x8 Ah[3][2], Al[3][2];               // unrolled -> registers (rule #20)
#pragma unroll
    for (int m = 0; m < 3; ++m) {
        const unsigned short* wh = wsp + m * 8192;
        const unsigned short* wl = wh + 4096;
#pragma unroll
        for (int ch = 0; ch < 2; ++ch) {
            Ah[m][ch] = *(const bf16x8*)(wh + (otile + lo16) * 64 + ch * 32 + lg * 8);
            Al[m][ch] = *(const bf16x8*)(wl + (otile + lo16) * 64 + ch * 32 + lg * 8);
        }
    }
    __syncthreads();

    float* outp[3] = { q, k, v };
    const float scl[3] = { LOG2E, 1.f, 1.f };   // fold exp2 prescale into q

#pragma unroll 2
    for (int jt = 0; jt < 4; ++jt) {         // unroll 2: bound hoisting (r12)
        const int jr = jt * 16 + lo16;
        const bf16x8 Bh0 = *(const bf16x8*)&xh [jr][lg * 8];
        const bf16x8 Bl0 = *(const bf16x8*)&xlo[jr][lg * 8];
        const bf16x8 Bh1 = *(const bf16x8*)&xh [jr][32 + lg * 8];
        const bf16x8 Bl1 = *(const bf16x8*)&xlo[jr][32 + lg * 8];
#pragma unroll
        for (int m = 0; m < 3; ++m) {
            f32x4 hh = {0.f, 0.f, 0.f, 0.f}; // 3 independent chains for ILP
            f32x4 hl = {0.f, 0.f, 0.f, 0.f};
            f32x4 lh = {0.f, 0.f, 0.f, 0.f};
            hh = __builtin_amdgcn_mfma_f32_16x16x32_bf16(Ah[m][0], Bh0, hh, 0, 0, 0);
            hl = __builtin_amdgcn_mfma_f32_16x16x32_bf16(Ah[m][0], Bl0, hl, 0, 0, 0);
            lh = __builtin_amdgcn_mfma_f32_16x16x32_bf16(Al[m][0], Bh0, lh, 0, 0, 0);
            hh = __builtin_amdgcn_mfma_f32_16x16x32_bf16(Ah[m][1], Bh1, hh, 0, 0, 0);
            hl = __builtin_amdgcn_mfma_f32_16x16x32_bf16(Ah[m][1], Bl1, hl, 0, 0, 0);
            lh = __builtin_amdgcn_mfma_f32_16x16x32_bf16(Al[m][1], Bh1, lh, 0, 0, 0);
            float* op = outp[m] + (otile + lg * 4) * SP + p0 + jt * 16 + lo16;
#pragma unroll
            for (int r = 0; r < 4; ++r)
                op[r * SP] = (hh[r] + hl[r] + lh[r]) * scl[m];  // coalesced 64B/row
        }
    }
}

// DPP shifts within 16-lane rows; bound_ctrl=1 -> out-of-row reads 0 =
// exactly the w-boundary zero-pad.
__device__ __forceinline__ float dpp_shr1(float x) {   // lane i <- lane i-1
    return __int_as_float(__builtin_amdgcn_mov_dpp(__float_as_int(x), 0x111, 0xf, 0xf, true));
}
__device__ __forceinline__ float dpp_shl1(float x) {   // lane i <- lane i+1
    return __int_as_float(__builtin_amdgcn_mov_dpp(__float_as_int(x), 0x101, 0xf, 0xf, true));
}

// attn v10 (UNCHANGED, 24.3us measured r19): thread = 1 float4 output;
// 9 (kd,kh) rows read DIRECTLY from global. unroll(1) on kd bounds loads.
// OOB rows: address clamped to 0, value zeroed (k=0 -> exp(q*rel), v=0).
template<int AXIS>
__device__ __forceinline__ void attn_walk(const float* __restrict__ kc,
                                          const float* __restrict__ vc,
                                          const float (&ql)[4],
                                          float r0, float r1, float r2,
                                          int wg, int dabs, int habs,
                                          float (&s)[4], float (&a)[4]) {
#pragma unroll 1
    for (int kd = 0; kd < 3; ++kd) {
        const float rdd = (kd == 0) ? r0 : (kd == 1) ? r1 : r2;
        const int dpg   = dabs - 1 + kd;
        const bool okd  = (unsigned)dpg < (unsigned)DD;
#pragma unroll
        for (int kh = 0; kh < 3; ++kh) {
            const float rkh = (kh == 0) ? r0 : (kh == 1) ? r1 : r2;
            const float rr  = (AXIS == 0) ? rdd : rkh;
            const int hpg   = habs - 1 + kh;
            const bool ok   = okd && ((unsigned)hpg < (unsigned)HH);
            const int off   = ok ? ((dpg * HH + hpg) * WW + wg * 4) : 0;
            float4 km = *(const float4*)(kc + off);
            float4 vm = *(const float4*)(vc + off);
            if (!ok) {
                km = make_float4(0.f, 0.f, 0.f, 0.f);
                vm = make_float4(0.f, 0.f, 0.f, 0.f);
            }
            const float kl = dpp_shr1(km.w), kr = dpp_shl1(km.x);
            const float vl = dpp_shr1(vm.w), vr = dpp_shl1(vm.x);
            float krow[6] = { kl, km.x, km.y, km.z, km.w, kr };
            const float vrow[6] = { vl, vm.x, vm.y, vm.z, vm.w, vr };
            if (AXIS != 2) {                 // hoist row-constant rel
#pragma unroll
                for (int j = 0; j < 6; ++j) krow[j] += rr;
            }
#pragma unroll
            for (int wi = 0; wi < 4; ++wi) {
                const float qv = ql[wi];
#pragma unroll
                for (int kw = 0; kw < 3; ++kw) {
                    const float arg = (AXIS == 2)
                                    ? (krow[wi + kw] + ((kw == 0) ? r0 : (kw == 1) ? r1 : r2))
                                    : krow[wi + kw];
                    const float e = __builtin_amdgcn_exp2f(qv * arg);
                    s[wi] += e;
                    a[wi] = fmaf(e, vrow[wi + kw], a[wi]);
                }
            }
        }
    }
}

__global__ __launch_bounds__(256) void attn(const float* __restrict__ kbuf,
                                            const float* __restrict__ vbuf,
                                            const float* __restrict__ qbuf,
                                            const float* __restrict__ rel_d,
                                            const float* __restrict__ rel_h,
                                            const float* __restrict__ rel_w,
                                            float* __restrict__ out) {
    const int dt = blockIdx.x;       // 0..3
    const int ht = blockIdx.y;       // 0..15
    const int o  = blockIdx.z;       // 0..63

    const int d0 = dt * 4;
    const int h0 = ht * 4;
    const int t  = threadIdx.x;

    const float* __restrict__ kc = kbuf + o * SP;
    const float* __restrict__ vc = vbuf + o * SP;

    const int wg = t & 15;           // float4 in w
    const int hl = (t >> 4) & 3;     // local h
    const int dl = t >> 6;           // local d (== wave id)

    const int dabs = d0 + dl;
    const int habs = h0 + hl;

    float ql[4];
    {
        const float4 q4 = *(const float4*)(qbuf + o * SP + (dabs * HH + habs) * WW + wg * 4);
        ql[0] = q4.x; ql[1] = q4.y;            // q pre-scaled by LOG2E in proj
        ql[2] = q4.z; ql[3] = q4.w;
    }

    float s[4] = {};
    float a[4] = {};

    if (o < 21) {
        attn_walk<0>(kc, vc, ql, rel_d[o * 3], rel_d[o * 3 + 1], rel_d[o * 3 + 2],
                     wg, dabs, habs, s, a);
    } else if (o < 42) {
        const int b = o - 21;
        attn_walk<1>(kc, vc, ql, rel_h[b * 3], rel_h[b * 3 + 1], rel_h[b * 3 + 2],
                     wg, dabs, habs, s, a);
    } else {
        const int b = o - 42;
        attn_walk<2>(kc, vc, ql, rel_w[b * 3], rel_w[b * 3 + 1], rel_w[b * 3 + 2],
                     wg, dabs, habs, s, a);
    }

    float4 ov;
    ov.x = a[0] * __builtin_amdgcn_rcpf(s[0]);
    ov.y = a[1] * __builtin_amdgcn_rcpf(s[1]);
    ov.z = a[2] * __builtin_amdgcn_rcpf(s[2]);
    ov.w = a[3] * __builtin_amdgcn_rcpf(s[3]);
    *(float4*)(out + o * SP + (dabs * HH + habs) * WW + wg * 4) = ov;
}

extern "C" void kernel_launch(void* const* d_in, const int* in_sizes, int n_in,
                              void* d_out, int out_size, void* d_ws, size_t ws_size,
                              hipStream_t stream) {
    const float* x     = (const float*)d_in[0];
    const float* w_q   = (const float*)d_in[1];
    const float* w_k   = (const float*)d_in[2];
    const float* w_v   = (const float*)d_in[3];
    const float* rel_d = (const float*)d_in[4];
    const float* rel_h = (const float*)d_in[5];
    const float* rel_w = (const float*)d_in[6];
    float* out = (float*)d_out;

    float* ws = (float*)d_ws;
    float* q  = ws;                              // [64][SP] fp32
    float* k  = ws + (size_t)COUT * SP;
    float* v  = ws + 2 * (size_t)COUT * SP;
    unsigned short* wsp = (unsigned short*)(ws + 3 * (size_t)COUT * SP);

    splitw<<<dim3(3), 256, 0, stream>>>(w_q, w_k, w_v, wsp);
    proj<<<dim3(SP / 64), 256, 0, stream>>>(x, wsp, q, k, v);
    attn<<<dim3(4, 16, 64), 256, 0, stream>>>(k, v, q, rel_d, rel_h, rel_w, out);
}